// Round 9
// baseline (479.230 us; speedup 1.0000x reference)
//
#include <hip/hip_runtime.h>
#include <hip/hip_cooperative_groups.h>
#include <math.h>

namespace cg = cooperative_groups;

#define EPSN 1e-8f
#define MAXBUCK 512          // buckets of 128 nodes; requires N < 65536 (ushort col)
#define NB 256               // blocks  (1 per CU -> cooperative co-residency guaranteed)
#define NT 512               // threads (8 waves)

typedef __attribute__((ext_vector_type(8))) short short8;
typedef __attribute__((ext_vector_type(4))) float f32x4;

static __device__ __forceinline__ unsigned short f2bf(float f) {
    union { float f; unsigned int u; } v; v.f = f;
    unsigned int u = v.u;
    return (unsigned short)((u + 0x7fffu + ((u >> 16) & 1u)) >> 16);  // RNE
}
static __device__ __forceinline__ float bf2f(unsigned short h) {
    union { unsigned int u; float f; } v; v.u = ((unsigned int)h) << 16;
    return v.f;
}
static __device__ __forceinline__ unsigned int pk2(float a, float b) {
    return (((unsigned int)f2bf(b)) << 16) | (unsigned int)f2bf(a);
}

struct MegaParams {
    const float* x; const int* src; const int* dst;
    const float* Ws0; const float* Wn0; const float* Ws1; const float* Wn1;
    unsigned short* A0; unsigned short* h1; float* S; float* Qp;
    unsigned short* B0t; unsigned short* B1t; float* bias;
    int* rowp; unsigned short* colb; unsigned int* pairs;
    int* ghist; int* boff; int* bcur;
    float* out; int N; int E; int nbuck;
};

#define ACC8(v) { a0 += bf2f((unsigned short)((v).x & 0xFFFFu)); a1 += bf2f((unsigned short)((v).x >> 16)); \
                  a2 += bf2f((unsigned short)((v).y & 0xFFFFu)); a3 += bf2f((unsigned short)((v).y >> 16)); \
                  a4 += bf2f((unsigned short)((v).z & 0xFFFFu)); a5 += bf2f((unsigned short)((v).z >> 16)); \
                  a6 += bf2f((unsigned short)((v).w & 0xFFFFu)); a7 += bf2f((unsigned short)((v).w >> 16)); }

__global__ void __launch_bounds__(NT, 2) mega_kernel(MegaParams p) {
    cg::grid_group grid = cg::this_grid();
    __shared__ __align__(16) char smem[64512];
    const int tid = threadIdx.x;
    const int bid = blockIdx.x;
    const int w = tid >> 6, lane = tid & 63;

    //================ P0: bucket hist | x->bf16 | weight prep ================
    {
        int* h = (int*)smem;
        for (int i = tid; i < MAXBUCK; i += NT) h[i] = 0;
        __syncthreads();
        int CH = (p.E + NB - 1) / NB;
        int lo = bid * CH, hi = min(p.E, lo + CH);
        for (int e = lo + tid; e < hi; e += NT) atomicAdd(&h[p.dst[e] >> 7], 1);
        __syncthreads();
        for (int i = tid; i < p.nbuck; i += NT) { int c = h[i]; if (c) atomicAdd(&p.ghist[i], c); }

        for (int u = bid * NT + tid; u < p.N * 8; u += NB * NT) {
            int n = u >> 3, s = u & 7;
            const float4* xp = (const float4*)(p.x + (size_t)n * 64 + s * 8);
            float4 v0 = xp[0], v1 = xp[1];
            short8 r;
            r[0] = (short)f2bf(v0.x); r[1] = (short)f2bf(v0.y);
            r[2] = (short)f2bf(v0.z); r[3] = (short)f2bf(v0.w);
            r[4] = (short)f2bf(v1.x); r[5] = (short)f2bf(v1.y);
            r[6] = (short)f2bf(v1.z); r[7] = (short)f2bf(v1.w);
            *(short8*)(&p.A0[(size_t)n * 160 + s * 8]) = r;
        }
        const int PT = 128 * 160 + 32 * 128 + 20;
        for (int t = bid * NT + tid; t < PT; t += NB * NT) {
            if (t < 128 * 160) {
                int n = t / 160, k = t % 160;
                float v = 0.f;
                if (k < 64) v = p.Ws0[k * 128 + n];
                else if (k < 128) v = p.Wn0[(k - 64) * 128 + n];
                else if (k == 128) v = p.Ws0[64 * 128 + n];
                else if (k == 129) v = p.Wn0[64 * 128 + n];
                p.B0t[n * 160 + k] = f2bf(v);
            } else if (t < 128 * 160 + 32 * 128) {
                int u2 = t - 128 * 160;
                int c = u2 / 128, k = u2 % 128;
                float v = 0.f;
                if (c < 10) v = p.Ws1[k * 10 + c];
                else if (c < 20) v = p.Wn1[k * 10 + (c - 10)];
                p.B1t[c * 128 + k] = f2bf(v);
            } else {
                int w2 = t - 128 * 160 - 32 * 128;
                p.bias[w2] = (w2 < 10) ? p.Ws1[128 * 10 + w2] : p.Wn1[128 * 10 + (w2 - 10)];
            }
        }
    }
    grid.sync();

    //================ P1: scan of bucket counts (block 0) ================
    if (bid == 0) {
        int* bufa = (int*)smem; int* bufb = bufa + MAXBUCK;
        int t = tid;  // NT == MAXBUCK
        int v = (t < p.nbuck) ? p.ghist[t] : 0;
        bufa[t] = v;
        __syncthreads();
        int* cur = bufa; int* nxt = bufb;
        for (int off2 = 1; off2 < MAXBUCK; off2 <<= 1) {
            int xv = cur[t];
            if (t >= off2) xv += cur[t - off2];
            nxt[t] = xv;
            __syncthreads();
            int* tmp = cur; cur = nxt; nxt = tmp;
        }
        int incl = cur[t], excl = incl - v;
        if (t < p.nbuck) { p.boff[t] = excl; p.bcur[t] = excl; }
        if (t == p.nbuck - 1) p.boff[p.nbuck] = incl;
        if (t == 0) p.rowp[p.N] = p.E;
    }
    grid.sync();

    //================ P2: binned scatter of packed (local_dst<<16 | src) ================
    {
        int* h = (int*)smem; int* bs = h + MAXBUCK;
        for (int i = tid; i < MAXBUCK; i += NT) h[i] = 0;
        __syncthreads();
        int CH = (p.E + NB - 1) / NB;
        int lo = bid * CH, hi = min(p.E, lo + CH);
        for (int e = lo + tid; e < hi; e += NT) atomicAdd(&h[p.dst[e] >> 7], 1);
        __syncthreads();
        for (int i = tid; i < MAXBUCK; i += NT) {
            int c = h[i];
            bs[i] = c ? atomicAdd(&p.bcur[i], c) : 0;
            h[i] = 0;
        }
        __syncthreads();
        for (int e = lo + tid; e < hi; e += NT) {
            int d = p.dst[e];
            int b = d >> 7;
            int idx = atomicAdd(&h[b], 1);
            p.pairs[bs[b] + idx] = (((unsigned int)(d & 127)) << 16) | (unsigned int)p.src[e];
        }
    }
    grid.sync();

    //================ P3: per-bucket finalize -> row_ptr + ushort col ================
    for (int b = bid; b < p.nbuck; b += NB) {
        int* lh = (int*)smem; int* ls = lh + 128; int* lc = ls + 128;
        int lo = p.boff[b], hi = p.boff[b + 1];
        for (int i = tid; i < 128; i += NT) lh[i] = 0;
        __syncthreads();
        for (int e = lo + tid; e < hi; e += NT) atomicAdd(&lh[p.pairs[e] >> 16], 1);
        __syncthreads();
        if (tid < 128) {
            int v = lh[tid];
            int incl = v;
#pragma unroll
            for (int off2 = 1; off2 < 64; off2 <<= 1) {
                int y = __shfl_up(incl, off2);
                if ((tid & 63) >= off2) incl += y;
            }
            ls[tid] = incl;
        }
        __syncthreads();
        if (tid < 128) {
            int v = lh[tid];
            int excl = ls[tid] - v + ((tid >= 64) ? ls[63] : 0);
            int node = b * 128 + tid;
            if (node < p.N) p.rowp[node] = lo + excl;
            lc[tid] = excl;
        }
        __syncthreads();
        for (int e = lo + tid; e < hi; e += NT) {
            unsigned int pr = p.pairs[e];
            int ld = pr >> 16;
            int idx = atomicAdd(&lc[ld], 1);
            p.colb[lo + idx] = (unsigned short)(pr & 0xFFFFu);
        }
        __syncthreads();
    }
    grid.sync();

    //================ P4: agg0 (8 groups x 8 lanes x uint4; 32 edges in flight) ================
    {
        int sub = lane >> 3, f8 = lane & 7;
        for (int n = bid * 8 + w; n < p.N; n += NB * 8) {
            int rs = p.rowp[n], re = p.rowp[n + 1];
            float a0 = 0.f, a1 = 0.f, a2 = 0.f, a3 = 0.f, a4 = 0.f, a5 = 0.f, a6 = 0.f, a7 = 0.f;
            for (int base = rs; base < re; base += 64) {
                int cnt = min(64, re - base);
                int e = 0;
                if (base + lane < re) e = (int)p.colb[base + lane];
                int j = 0;
                for (; j + 32 <= cnt; j += 32) {
                    int s0 = __shfl(e, j + sub);
                    int s1 = __shfl(e, j + 8 + sub);
                    int s2 = __shfl(e, j + 16 + sub);
                    int s3 = __shfl(e, j + 24 + sub);
                    uint4 v0 = *(const uint4*)(&p.A0[(size_t)s0 * 160 + f8 * 8]);
                    uint4 v1 = *(const uint4*)(&p.A0[(size_t)s1 * 160 + f8 * 8]);
                    uint4 v2 = *(const uint4*)(&p.A0[(size_t)s2 * 160 + f8 * 8]);
                    uint4 v3 = *(const uint4*)(&p.A0[(size_t)s3 * 160 + f8 * 8]);
                    ACC8(v0); ACC8(v1); ACC8(v2); ACC8(v3);
                }
                for (; j < cnt; j += 8) {
                    int idx = j + sub;
                    int s = __shfl(e, idx < cnt ? idx : (cnt - 1));
                    if (idx < cnt) {
                        uint4 v = *(const uint4*)(&p.A0[(size_t)s * 160 + f8 * 8]);
                        ACC8(v);
                    }
                }
            }
#define RED8(a) { a += __shfl_xor(a, 8); a += __shfl_xor(a, 16); a += __shfl_xor(a, 32); }
            RED8(a0); RED8(a1); RED8(a2); RED8(a3); RED8(a4); RED8(a5); RED8(a6); RED8(a7);
            float deg = (float)(re - rs);
            float scale = 1.0f / fmaxf(deg, 1.0f);
            if (sub == 0) {
                uint4 o;
                o.x = pk2(a0 * scale, a1 * scale);
                o.y = pk2(a2 * scale, a3 * scale);
                o.z = pk2(a4 * scale, a5 * scale);
                o.w = pk2(a6 * scale, a7 * scale);
                *(uint4*)(&p.A0[(size_t)n * 160 + 64 + f8 * 8]) = o;
            } else if (sub == 1) {
                uint2 z = {0u, 0u};
                if (f8 == 0) z.x = ((unsigned int)f2bf(deg * scale) << 16) | 0x3F80u;  // (1.0, degscale)
                *(uint2*)(&p.A0[(size_t)n * 160 + 128 + f8 * 4]) = z;
            }
        }
    }
    grid.sync();

    //================ P5: GEMM0  h1 = relu(normalize(A0 @ B0)) ================
    {
        unsigned short* Bs = (unsigned short*)smem;      // 128 x 168
        unsigned short* As = Bs + 128 * 168;             // 64 x 168
        for (int i = tid; i < 128 * 20; i += NT) {
            int r = i / 20, c = i % 20;
            *(uint4*)(&Bs[r * 168 + c * 8]) = *(const uint4*)(&p.B0t[r * 160 + c * 8]);
        }
        __syncthreads();
        int lo16 = lane & 15, hi4 = lane >> 4;
        int rw = w >> 1, fh = w & 1;   // wave: rows rw*16.., f-half fh (4 of 8 f-blocks)
        int ntile = (p.N + 63) >> 6;
        for (int tile = bid; tile < ntile; tile += NB) {
            for (int i = tid; i < 64 * 20; i += NT) {
                int r = i / 20, c = i % 20;
                int gr = tile * 64 + r;
                uint4 v = {0, 0, 0, 0};
                if (gr < p.N) v = *(const uint4*)(&p.A0[(size_t)gr * 160 + c * 8]);
                *(uint4*)(&As[r * 168 + c * 8]) = v;
            }
            __syncthreads();
            f32x4 acc[4];
#pragma unroll
            for (int f = 0; f < 4; ++f) acc[f] = (f32x4){0.f, 0.f, 0.f, 0.f};
#pragma unroll
            for (int ks = 0; ks < 5; ++ks) {
                short8 a = *(const short8*)(&As[(rw * 16 + lo16) * 168 + ks * 32 + hi4 * 8]);
#pragma unroll
                for (int f = 0; f < 4; ++f) {
                    short8 b = *(const short8*)(&Bs[((fh * 4 + f) * 16 + lo16) * 168 + ks * 32 + hi4 * 8]);
                    acc[f] = __builtin_amdgcn_mfma_f32_16x16x32_bf16(a, b, acc[f], 0, 0, 0);
                }
            }
            __syncthreads();                       // As free -> reuse as norm scratch
            float* sred = (float*)As;              // [2][64]
#pragma unroll
            for (int j = 0; j < 4; ++j) {
                float s = 0.f;
#pragma unroll
                for (int f = 0; f < 4; ++f) s += acc[f][j] * acc[f][j];
#pragma unroll
                for (int m = 1; m < 16; m <<= 1) s += __shfl_xor(s, m);
                if (lo16 == 0) sred[fh * 64 + rw * 16 + hi4 * 4 + j] = s;
            }
            __syncthreads();
#pragma unroll
            for (int j = 0; j < 4; ++j) {
                int rit = rw * 16 + hi4 * 4 + j;
                float stot = sred[rit] + sred[64 + rit];
                float inv = 1.0f / (sqrtf(stot) + EPSN);
                int gr = tile * 64 + rit;
                if (gr < p.N) {
#pragma unroll
                    for (int f = 0; f < 4; ++f)
                        p.h1[(size_t)gr * 128 + (fh * 4 + f) * 16 + lo16] = f2bf(fmaxf(acc[f][j] * inv, 0.f));
                }
            }
            __syncthreads();
        }
    }
    grid.sync();

    //================ P6: GEMM1  S = h1@Ws1+b ; Qp = [h1@Wn1+b | 0] ================
    {
        unsigned short* Bs = (unsigned short*)smem;      // 32 x 136
        unsigned short* As = Bs + 32 * 136;              // 128 x 136
        for (int i = tid; i < 32 * 16; i += NT) {
            int r = i / 16, c = i % 16;
            *(uint4*)(&Bs[r * 136 + c * 8]) = *(const uint4*)(&p.B1t[r * 128 + c * 8]);
        }
        __syncthreads();
        int lo16 = lane & 15, hi4 = lane >> 4;
        int ntile = (p.N + 127) >> 7;
        for (int tile = bid; tile < ntile; tile += NB) {
            for (int i = tid; i < 128 * 16; i += NT) {
                int r = i / 16, c = i % 16;
                int gr = tile * 128 + r;
                uint4 v = {0, 0, 0, 0};
                if (gr < p.N) v = *(const uint4*)(&p.h1[(size_t)gr * 128 + c * 8]);
                *(uint4*)(&As[r * 136 + c * 8]) = v;
            }
            __syncthreads();
            f32x4 acc0 = (f32x4){0.f, 0.f, 0.f, 0.f};
            f32x4 acc1 = (f32x4){0.f, 0.f, 0.f, 0.f};
#pragma unroll
            for (int ks = 0; ks < 4; ++ks) {
                short8 b0 = *(const short8*)(&Bs[lo16 * 136 + ks * 32 + hi4 * 8]);
                short8 b1 = *(const short8*)(&Bs[(16 + lo16) * 136 + ks * 32 + hi4 * 8]);
                short8 a  = *(const short8*)(&As[(w * 16 + lo16) * 136 + ks * 32 + hi4 * 8]);
                acc0 = __builtin_amdgcn_mfma_f32_16x16x32_bf16(a, b0, acc0, 0, 0, 0);
                acc1 = __builtin_amdgcn_mfma_f32_16x16x32_bf16(a, b1, acc1, 0, 0, 0);
            }
#pragma unroll
            for (int j = 0; j < 4; ++j) {
                int gr = tile * 128 + w * 16 + hi4 * 4 + j;
                if (gr < p.N) {
                    float v0 = acc0[j] + p.bias[lo16];
                    if (lo16 < 10) p.S[(size_t)gr * 10 + lo16] = v0;
                    else           p.Qp[(size_t)gr * 16 + (lo16 - 10)] = v0;              // cols 0..5
                    if (lo16 < 4)       p.Qp[(size_t)gr * 16 + 6 + lo16] = acc1[j] + p.bias[16 + lo16]; // 6..9
                    else if (lo16 < 10) p.Qp[(size_t)gr * 16 + 6 + lo16] = 0.f;           // pad 10..15
                }
            }
            __syncthreads();
        }
    }
    grid.sync();

    //================ P7: final  out = log_softmax(normalize(S + meanGather(Qp))) ================
    {
        int sub = lane >> 3, f8 = lane & 7;
        for (int n = bid * 8 + w; n < p.N; n += NB * 8) {
            int rs = p.rowp[n], re = p.rowp[n + 1];
            float qx = 0.f, qy = 0.f;
            for (int base = rs; base < re; base += 64) {
                int cnt = min(64, re - base);
                int e = 0;
                if (base + lane < re) e = (int)p.colb[base + lane];
                int j = 0;
                for (; j + 32 <= cnt; j += 32) {
                    int s0 = __shfl(e, j + sub);
                    int s1 = __shfl(e, j + 8 + sub);
                    int s2 = __shfl(e, j + 16 + sub);
                    int s3 = __shfl(e, j + 24 + sub);
                    float2 v0 = *(const float2*)(&p.Qp[(size_t)s0 * 16 + f8 * 2]);
                    float2 v1 = *(const float2*)(&p.Qp[(size_t)s1 * 16 + f8 * 2]);
                    float2 v2 = *(const float2*)(&p.Qp[(size_t)s2 * 16 + f8 * 2]);
                    float2 v3 = *(const float2*)(&p.Qp[(size_t)s3 * 16 + f8 * 2]);
                    qx += v0.x + v1.x + v2.x + v3.x;
                    qy += v0.y + v1.y + v2.y + v3.y;
                }
                for (; j < cnt; j += 8) {
                    int idx = j + sub;
                    int s = __shfl(e, idx < cnt ? idx : (cnt - 1));
                    if (idx < cnt) {
                        float2 v = *(const float2*)(&p.Qp[(size_t)s * 16 + f8 * 2]);
                        qx += v.x; qy += v.y;
                    }
                }
            }
            RED8(qx); RED8(qy);
            float deg = (float)(re - rs);
            float scale = 1.0f / fmaxf(deg, 1.0f);
            float px = 0.f, py = 0.f;
            if (f8 < 5) {
                px = p.S[(size_t)n * 10 + 2 * f8]     + qx * scale;
                py = p.S[(size_t)n * 10 + 2 * f8 + 1] + qy * scale;
            }
            float ss = px * px + py * py;
            ss += __shfl_xor(ss, 1); ss += __shfl_xor(ss, 2); ss += __shfl_xor(ss, 4);
            float inv = 1.0f / (sqrtf(ss) + EPSN);
            px *= inv; py *= inv;
            float mx = (f8 < 5) ? fmaxf(px, py) : -INFINITY;
            mx = fmaxf(mx, __shfl_xor(mx, 1)); mx = fmaxf(mx, __shfl_xor(mx, 2)); mx = fmaxf(mx, __shfl_xor(mx, 4));
            float se = (f8 < 5) ? (expf(px - mx) + expf(py - mx)) : 0.f;
            se += __shfl_xor(se, 1); se += __shfl_xor(se, 2); se += __shfl_xor(se, 4);
            float ls = logf(se) + mx;
            if (sub == 0 && f8 < 5) {
                p.out[(size_t)n * 10 + 2 * f8]     = px - ls;
                p.out[(size_t)n * 10 + 2 * f8 + 1] = py - ls;
            }
        }
    }
}

extern "C" void kernel_launch(void* const* d_in, const int* in_sizes, int n_in,
                              void* d_out, int out_size, void* d_ws, size_t ws_size,
                              hipStream_t stream) {
    const float* x   = (const float*)d_in[0];
    const int*   ei  = (const int*)d_in[1];
    const float* Ws0 = (const float*)d_in[2];
    const float* Wn0 = (const float*)d_in[3];
    const float* Ws1 = (const float*)d_in[4];
    const float* Wn1 = (const float*)d_in[5];

    int N = in_sizes[0] / 64;
    int E = in_sizes[1] / 2;
    int nbuck = (N + 127) / 128;

    char* ws = (char*)d_ws;
    size_t off = 0;
    unsigned short* A0   = (unsigned short*)(ws + off); off += (size_t)N * 160 * 2;
    unsigned short* h1   = (unsigned short*)(ws + off); off += (size_t)N * 128 * 2;
    float*          S    = (float*)(ws + off);          off += (size_t)N * 10 * 4;
    float*          Qp   = (float*)(ws + off);          off += (size_t)N * 16 * 4;
    unsigned short* B0t  = (unsigned short*)(ws + off); off += 128 * 160 * 2;
    unsigned short* B1t  = (unsigned short*)(ws + off); off += 32 * 128 * 2;
    float*          bias = (float*)(ws + off);          off += 128;
    int*            rowp = (int*)(ws + off);            off += ((size_t)N + 4) * 4;
    unsigned short* colb = (unsigned short*)(ws + off); off += ((size_t)E + 8) * 2;
    unsigned int*   pairs= (unsigned int*)(ws + off);   off += (size_t)E * 4;
    int*            ghist= (int*)(ws + off);            off += MAXBUCK * 4;
    int*            boff = (int*)(ws + off);            off += (MAXBUCK + 1) * 4;
    int*            bcur = (int*)(ws + off);            off += MAXBUCK * 4;

    MegaParams p;
    p.x = x; p.src = ei; p.dst = ei + E;
    p.Ws0 = Ws0; p.Wn0 = Wn0; p.Ws1 = Ws1; p.Wn1 = Wn1;
    p.A0 = A0; p.h1 = h1; p.S = S; p.Qp = Qp;
    p.B0t = B0t; p.B1t = B1t; p.bias = bias;
    p.rowp = rowp; p.colb = colb; p.pairs = pairs;
    p.ghist = ghist; p.boff = boff; p.bcur = bcur;
    p.out = (float*)d_out; p.N = N; p.E = E; p.nbuck = nbuck;

    hipMemsetAsync(ghist, 0, MAXBUCK * 4, stream);
    void* args[] = { &p };
    hipLaunchCooperativeKernel((const void*)mega_kernel, dim3(NB), dim3(NT), args, 0, stream);
}

// Round 10
// 184.252 us; speedup vs baseline: 2.6009x; 2.6009x over previous
//
#include <hip/hip_runtime.h>
#include <hip/hip_bf16.h>
#include <math.h>

#define EPSN 1e-8f
#define MAXBUCK 512          // buckets of 128 nodes; requires N < 65536 (ushort col)

typedef __attribute__((ext_vector_type(8))) short short8;
typedef __attribute__((ext_vector_type(4))) float f32x4;

static __device__ __forceinline__ unsigned short f2bf(float f) {
    union { float f; unsigned int u; } v; v.f = f;
    unsigned int u = v.u;
    return (unsigned short)((u + 0x7fffu + ((u >> 16) & 1u)) >> 16);  // RNE
}
static __device__ __forceinline__ float bf2f(unsigned short h) {
    union { unsigned int u; float f; } v; v.u = ((unsigned int)h) << 16;
    return v.f;
}
static __device__ __forceinline__ unsigned int pk2(float a, float b) {
    return (((unsigned int)f2bf(b)) << 16) | (unsigned int)f2bf(a);
}

// ================= fused pre: bucket hist | weight prep | x->bf16 =================
// A0 row layout: [ x(0..63) | neigh(64..127) | 1.0(128) degscale(129) | 0 pad(130..159) ]
// B0t[n][k]: k<64 -> Ws0[k][n]; 64..127 -> Wn0[k-64][n]; 128 -> Ws0[64][n]; 129 -> Wn0[64][n]
__global__ void fused_pre(const int* __restrict__ dst, int* __restrict__ ghist, int E, int nbuck,
                          const float* __restrict__ Ws0, const float* __restrict__ Wn0,
                          const float* __restrict__ Ws1, const float* __restrict__ Wn1,
                          unsigned short* __restrict__ B0t, unsigned short* __restrict__ B1t,
                          float* __restrict__ bias,
                          const float* __restrict__ x, unsigned short* __restrict__ A0, int N,
                          int histB, int prepB) {
    int b = blockIdx.x;
    if (b < histB) {
        __shared__ int h[MAXBUCK];
        for (int i = threadIdx.x; i < MAXBUCK; i += 256) h[i] = 0;
        __syncthreads();
        int CH = (E + histB - 1) / histB;
        int lo = b * CH, hi = min(E, lo + CH);
        for (int e = lo + (int)threadIdx.x; e < hi; e += 256) atomicAdd(&h[dst[e] >> 7], 1);
        __syncthreads();
        for (int i = threadIdx.x; i < nbuck; i += 256) if (h[i]) atomicAdd(&ghist[i], h[i]);
        return;
    }
    if (b < histB + prepB) {
        int t = (b - histB) * 256 + threadIdx.x;
        if (t < 128 * 160) {
            int n = t / 160, k = t % 160;
            float v = 0.f;
            if (k < 64) v = Ws0[k * 128 + n];
            else if (k < 128) v = Wn0[(k - 64) * 128 + n];
            else if (k == 128) v = Ws0[64 * 128 + n];
            else if (k == 129) v = Wn0[64 * 128 + n];
            B0t[n * 160 + k] = f2bf(v);
        }
        int u = t - 128 * 160;
        if (u >= 0 && u < 32 * 128) {
            int c = u / 128, k = u % 128;
            float v = 0.f;
            if (c < 10) v = Ws1[k * 10 + c];
            else if (c < 20) v = Wn1[k * 10 + (c - 10)];
            B1t[c * 128 + k] = f2bf(v);
        }
        int w = t - 128 * 160 - 32 * 128;
        if (w >= 0 && w < 20) bias[w] = (w < 10) ? Ws1[128 * 10 + w] : Wn1[128 * 10 + (w - 10)];
        return;
    }
    int u = (b - histB - prepB) * 256 + threadIdx.x;   // u = n*8 + s
    if (u >= N * 8) return;
    int n = u >> 3, s = u & 7;
    const float4* xp = (const float4*)(x + (size_t)n * 64 + s * 8);
    float4 v0 = xp[0], v1 = xp[1];
    short8 r;
    r[0] = (short)f2bf(v0.x); r[1] = (short)f2bf(v0.y);
    r[2] = (short)f2bf(v0.z); r[3] = (short)f2bf(v0.w);
    r[4] = (short)f2bf(v1.x); r[5] = (short)f2bf(v1.y);
    r[6] = (short)f2bf(v1.z); r[7] = (short)f2bf(v1.w);
    *(short8*)(&A0[(size_t)n * 160 + s * 8]) = r;
}

// ================= bucket scan (1 block) =================
__global__ void bucket_scan(const int* __restrict__ ghist, int* __restrict__ boff,
                            int* __restrict__ bcur, int nbuck, int E,
                            int* __restrict__ row_ptr, int N) {
    __shared__ int bufa[MAXBUCK], bufb[MAXBUCK];
    int t = threadIdx.x;  // MAXBUCK threads
    int v = (t < nbuck) ? ghist[t] : 0;
    bufa[t] = v;
    __syncthreads();
    int* cur = bufa; int* nxt = bufb;
    for (int off = 1; off < MAXBUCK; off <<= 1) {
        int xv = cur[t];
        if (t >= off) xv += cur[t - off];
        nxt[t] = xv;
        __syncthreads();
        int* tmp = cur; cur = nxt; nxt = tmp;
    }
    int incl = cur[t];
    int excl = incl - v;
    if (t < nbuck) { boff[t] = excl; bcur[t] = excl; }
    if (t == nbuck - 1) boff[nbuck] = incl;   // == E
    if (t == 0) row_ptr[N] = E;
}

// ================= binned scatter of packed (local_dst<<16 | src) =================
__global__ void bucket_scatter(const int* __restrict__ src, const int* __restrict__ dst,
                               int* __restrict__ bcur, unsigned int* __restrict__ pairs,
                               int E) {
    __shared__ int h[MAXBUCK];
    __shared__ int bs[MAXBUCK];
    for (int i = threadIdx.x; i < MAXBUCK; i += 256) h[i] = 0;
    __syncthreads();
    int CH = (E + gridDim.x - 1) / gridDim.x;
    int lo = blockIdx.x * CH, hi = min(E, lo + CH);
    for (int e = lo + (int)threadIdx.x; e < hi; e += 256) atomicAdd(&h[dst[e] >> 7], 1);
    __syncthreads();
    for (int i = threadIdx.x; i < MAXBUCK; i += 256) {
        int c = h[i];
        bs[i] = c ? atomicAdd(&bcur[i], c) : 0;
        h[i] = 0;
    }
    __syncthreads();
    for (int e = lo + (int)threadIdx.x; e < hi; e += 256) {
        int d = dst[e];
        int b = d >> 7;
        int idx = atomicAdd(&h[b], 1);
        pairs[bs[b] + idx] = (((unsigned int)(d & 127)) << 16) | (unsigned int)src[e];
    }
}

// ================= per-bucket finalize -> row_ptr + ushort col =================
__global__ void csr_finalize(const unsigned int* __restrict__ pairs, const int* __restrict__ boff,
                             int* __restrict__ row_ptr, unsigned short* __restrict__ col,
                             int N) {
    __shared__ int lh[128], ls[128], lc[128];
    int b = blockIdx.x, t = threadIdx.x;  // 256 threads
    int lo = boff[b], hi = boff[b + 1];
    for (int i = t; i < 128; i += 256) lh[i] = 0;
    __syncthreads();
    for (int e = lo + t; e < hi; e += 256) atomicAdd(&lh[pairs[e] >> 16], 1);
    __syncthreads();
    if (t < 128) {
        int v = lh[t];
        int incl = v;
#pragma unroll
        for (int off = 1; off < 64; off <<= 1) {
            int y = __shfl_up(incl, off);
            if ((t & 63) >= off) incl += y;
        }
        ls[t] = incl;
    }
    __syncthreads();
    if (t < 128) {
        int v = lh[t];
        int excl = ls[t] - v + ((t >= 64) ? ls[63] : 0);
        int node = b * 128 + t;
        if (node < N) row_ptr[node] = lo + excl;
        lc[t] = excl;
    }
    __syncthreads();
    for (int e = lo + t; e < hi; e += 256) {
        unsigned int p = pairs[e];
        int ld = p >> 16;
        int idx = atomicAdd(&lc[ld], 1);
        col[lo + idx] = (unsigned short)(p & 0xFFFFu);
    }
}

// ================= agg0: wave-per-node scalar-lane gather-mean (proven r6 form) =================
// lane = feature; chunked col load + uniform-index shfl broadcast (readlane), 4-deep unroll
__global__ void agg0_kernel(const int* __restrict__ row_ptr, const unsigned short* __restrict__ col,
                            unsigned short* __restrict__ A0, int N) {
    int n = (int)((blockIdx.x * blockDim.x + threadIdx.x) >> 6);
    if (n >= N) return;
    int lane = threadIdx.x & 63;
    int rs = row_ptr[n], re = row_ptr[n + 1];
    float acc = 0.f;
    for (int base = rs; base < re; base += 64) {
        int cnt = min(64, re - base);
        int e = 0;
        if (base + lane < re) e = (int)col[base + lane];
        int j = 0;
        for (; j + 3 < cnt; j += 4) {
            int s0 = __shfl(e, j), s1 = __shfl(e, j + 1);
            int s2 = __shfl(e, j + 2), s3 = __shfl(e, j + 3);
            float v0 = bf2f(A0[(size_t)s0 * 160 + lane]);
            float v1 = bf2f(A0[(size_t)s1 * 160 + lane]);
            float v2 = bf2f(A0[(size_t)s2 * 160 + lane]);
            float v3 = bf2f(A0[(size_t)s3 * 160 + lane]);
            acc += v0; acc += v1; acc += v2; acc += v3;
        }
        for (; j < cnt; ++j) {
            int s = __shfl(e, j);
            acc += bf2f(A0[(size_t)s * 160 + lane]);
        }
    }
    float deg = (float)(re - rs);
    float scale = 1.0f / fmaxf(deg, 1.0f);
    unsigned short* row = A0 + (size_t)n * 160;
    row[64 + lane] = f2bf(acc * scale);                 // neigh cols 64..127
    if (lane == 0) *(unsigned int*)(&row[128]) = pk2(1.0f, deg * scale);  // (1.0, degscale)
    if (lane >= 1 && lane < 16) *(unsigned int*)(&row[128 + lane * 2]) = 0u;  // pad 130..159
}

// ================= GEMM0: h1 = relu(normalize(A0 @ B0)) =================
__global__ void __launch_bounds__(256)
gemm0_kernel(const unsigned short* __restrict__ A0, const unsigned short* __restrict__ B0t,
             unsigned short* __restrict__ h1, int N) {
    __shared__ unsigned short As[64 * 168];
    __shared__ unsigned short Bs[128 * 168];
    int t = threadIdx.x, blk = blockIdx.x;
    for (int i = t; i < 128 * 20; i += 256) {
        int r = i / 20, c = i % 20;
        *(uint4*)(&Bs[r * 168 + c * 8]) = *(const uint4*)(&B0t[r * 160 + c * 8]);
    }
    for (int i = t; i < 64 * 20; i += 256) {
        int r = i / 20, c = i % 20;
        int gr = blk * 64 + r;
        uint4 v = {0, 0, 0, 0};
        if (gr < N) v = *(const uint4*)(&A0[(size_t)gr * 160 + c * 8]);
        *(uint4*)(&As[r * 168 + c * 8]) = v;
    }
    __syncthreads();

    int wave = t >> 6, lane = t & 63;
    int lo = lane & 15, hi = lane >> 4;
    f32x4 acc[8];
#pragma unroll
    for (int f = 0; f < 8; ++f) acc[f] = (f32x4){0.f, 0.f, 0.f, 0.f};

#pragma unroll
    for (int ks = 0; ks < 5; ++ks) {
        short8 a = *(const short8*)(&As[(wave * 16 + lo) * 168 + ks * 32 + hi * 8]);
#pragma unroll
        for (int f = 0; f < 8; ++f) {
            short8 b = *(const short8*)(&Bs[(f * 16 + lo) * 168 + ks * 32 + hi * 8]);
            acc[f] = __builtin_amdgcn_mfma_f32_16x16x32_bf16(a, b, acc[f], 0, 0, 0);
        }
    }
#pragma unroll
    for (int j = 0; j < 4; ++j) {
        float s = 0.f;
#pragma unroll
        for (int f = 0; f < 8; ++f) s += acc[f][j] * acc[f][j];
#pragma unroll
        for (int m = 1; m < 16; m <<= 1) s += __shfl_xor(s, m);
        float inv = 1.0f / (sqrtf(s) + EPSN);
        int gr = blk * 64 + wave * 16 + hi * 4 + j;
        if (gr < N) {
#pragma unroll
            for (int f = 0; f < 8; ++f)
                h1[(size_t)gr * 128 + f * 16 + lo] = f2bf(fmaxf(acc[f][j] * inv, 0.f));
        }
    }
}

// ================= GEMM1: S[N][10] = h1@Ws1+b ; Qp[N][16] = [h1@Wn1+b | 0 pad] =================
__global__ void __launch_bounds__(256)
gemm1_kernel(const unsigned short* __restrict__ h1, const unsigned short* __restrict__ B1t,
             const float* __restrict__ bias, float* __restrict__ S, float* __restrict__ Qp, int N) {
    __shared__ unsigned short As[128 * 136];
    __shared__ unsigned short Bs[32 * 136];
    int t = threadIdx.x, blk = blockIdx.x;
    for (int i = t; i < 32 * 16; i += 256) {
        int r = i / 16, c = i % 16;
        *(uint4*)(&Bs[r * 136 + c * 8]) = *(const uint4*)(&B1t[r * 128 + c * 8]);
    }
    for (int i = t; i < 128 * 16; i += 256) {
        int r = i / 16, c = i % 16;
        int gr = blk * 128 + r;
        uint4 v = {0, 0, 0, 0};
        if (gr < N) v = *(const uint4*)(&h1[(size_t)gr * 128 + c * 8]);
        *(uint4*)(&As[r * 136 + c * 8]) = v;
    }
    __syncthreads();

    int wave = t >> 6, lane = t & 63, lo = lane & 15, hi = lane >> 4;
    f32x4 acc[2][2];
#pragma unroll
    for (int m = 0; m < 2; ++m) { acc[m][0] = (f32x4){0,0,0,0}; acc[m][1] = (f32x4){0,0,0,0}; }

#pragma unroll
    for (int ks = 0; ks < 4; ++ks) {
        short8 b0 = *(const short8*)(&Bs[lo * 136 + ks * 32 + hi * 8]);
        short8 b1 = *(const short8*)(&Bs[(16 + lo) * 136 + ks * 32 + hi * 8]);
#pragma unroll
        for (int m = 0; m < 2; ++m) {
            short8 a = *(const short8*)(&As[(wave * 32 + m * 16 + lo) * 136 + ks * 32 + hi * 8]);
            acc[m][0] = __builtin_amdgcn_mfma_f32_16x16x32_bf16(a, b0, acc[m][0], 0, 0, 0);
            acc[m][1] = __builtin_amdgcn_mfma_f32_16x16x32_bf16(a, b1, acc[m][1], 0, 0, 0);
        }
    }
#pragma unroll
    for (int m = 0; m < 2; ++m)
#pragma unroll
        for (int j = 0; j < 4; ++j) {
            int gr = blk * 128 + wave * 32 + m * 16 + hi * 4 + j;
            if (gr < N) {
                float v0 = acc[m][0][j] + bias[lo];
                if (lo < 10) S[(size_t)gr * 10 + lo] = v0;
                else         Qp[(size_t)gr * 16 + (lo - 10)] = v0;                          // cols 0..5
                if (lo < 4)       Qp[(size_t)gr * 16 + 6 + lo] = acc[m][1][j] + bias[16 + lo]; // 6..9
                else if (lo < 10) Qp[(size_t)gr * 16 + 6 + lo] = 0.f;                       // pad 10..15
            }
        }
}

// ================= final: thread-per-node; line-aligned float4 Qp gather; log_softmax =================
__global__ void final_kernel(const float* __restrict__ S, const float* __restrict__ Qp,
                             const int* __restrict__ row_ptr, const unsigned short* __restrict__ col,
                             float* __restrict__ out, int N) {
    int n = blockIdx.x * blockDim.x + threadIdx.x;
    if (n >= N) return;
    int rs = row_ptr[n], re = row_ptr[n + 1];
    float q0 = 0.f, q1 = 0.f, q2 = 0.f, q3 = 0.f, q4 = 0.f;
    float q5 = 0.f, q6 = 0.f, q7 = 0.f, q8 = 0.f, q9 = 0.f;
    int e = rs;
    for (; e + 1 < re; e += 2) {
        int c0 = (int)col[e], c1 = (int)col[e + 1];
        const float4* r0 = (const float4*)(&Qp[(size_t)c0 * 16]);
        const float4* r1 = (const float4*)(&Qp[(size_t)c1 * 16]);
        float4 a0 = r0[0], b0 = r0[1];
        float2 t0 = *(const float2*)(&Qp[(size_t)c0 * 16 + 8]);
        float4 a1 = r1[0], b1 = r1[1];
        float2 t1 = *(const float2*)(&Qp[(size_t)c1 * 16 + 8]);
        q0 += a0.x + a1.x; q1 += a0.y + a1.y; q2 += a0.z + a1.z; q3 += a0.w + a1.w;
        q4 += b0.x + b1.x; q5 += b0.y + b1.y; q6 += b0.z + b1.z; q7 += b0.w + b1.w;
        q8 += t0.x + t1.x; q9 += t0.y + t1.y;
    }
    if (e < re) {
        int c0 = (int)col[e];
        const float4* r0 = (const float4*)(&Qp[(size_t)c0 * 16]);
        float4 a0 = r0[0], b0 = r0[1];
        float2 t0 = *(const float2*)(&Qp[(size_t)c0 * 16 + 8]);
        q0 += a0.x; q1 += a0.y; q2 += a0.z; q3 += a0.w;
        q4 += b0.x; q5 += b0.y; q6 += b0.z; q7 += b0.w;
        q8 += t0.x; q9 += t0.y;
    }
    float deg = (float)(re - rs);
    float scale = 1.0f / fmaxf(deg, 1.0f);
    const float* Sr = &S[(size_t)n * 10];
    float p[10];
    p[0] = Sr[0] + q0 * scale; p[1] = Sr[1] + q1 * scale;
    p[2] = Sr[2] + q2 * scale; p[3] = Sr[3] + q3 * scale;
    p[4] = Sr[4] + q4 * scale; p[5] = Sr[5] + q5 * scale;
    p[6] = Sr[6] + q6 * scale; p[7] = Sr[7] + q7 * scale;
    p[8] = Sr[8] + q8 * scale; p[9] = Sr[9] + q9 * scale;
    float ss = 0.f;
#pragma unroll
    for (int j = 0; j < 10; ++j) ss = fmaf(p[j], p[j], ss);
    float inv = 1.0f / (sqrtf(ss) + EPSN);
    float m = -INFINITY;
#pragma unroll
    for (int j = 0; j < 10; ++j) { p[j] *= inv; m = fmaxf(m, p[j]); }
    float se = 0.f;
#pragma unroll
    for (int j = 0; j < 10; ++j) se += expf(p[j] - m);
    float ls = logf(se) + m;
#pragma unroll
    for (int j = 0; j < 10; ++j) out[(size_t)n * 10 + j] = p[j] - ls;
}

extern "C" void kernel_launch(void* const* d_in, const int* in_sizes, int n_in,
                              void* d_out, int out_size, void* d_ws, size_t ws_size,
                              hipStream_t stream) {
    const float* x   = (const float*)d_in[0];
    const int*   ei  = (const int*)d_in[1];
    const float* Ws0 = (const float*)d_in[2];
    const float* Wn0 = (const float*)d_in[3];
    const float* Ws1 = (const float*)d_in[4];
    const float* Wn1 = (const float*)d_in[5];

    int N = in_sizes[0] / 64;
    int E = in_sizes[1] / 2;
    const int* src = ei;
    const int* dst = ei + E;
    int nbuck = (N + 127) / 128;

    char* ws = (char*)d_ws;
    size_t off = 0;
    unsigned short* A0   = (unsigned short*)(ws + off); off += (size_t)N * 160 * 2;
    unsigned short* h1   = (unsigned short*)(ws + off); off += (size_t)N * 128 * 2;
    float*          S    = (float*)(ws + off);          off += (size_t)N * 10 * 4;
    float*          Qp   = (float*)(ws + off);          off += (size_t)N * 16 * 4;
    unsigned short* B0t  = (unsigned short*)(ws + off); off += 128 * 160 * 2;
    unsigned short* B1t  = (unsigned short*)(ws + off); off += 32 * 128 * 2;
    float*          bias = (float*)(ws + off);          off += 128;
    int*            rowp = (int*)(ws + off);            off += ((size_t)N + 4) * 4;
    unsigned short* colb = (unsigned short*)(ws + off); off += ((size_t)E + 8) * 2;
    unsigned int*   pairs= (unsigned int*)(ws + off);   off += (size_t)E * 4;
    int*            ghist= (int*)(ws + off);            off += MAXBUCK * 4;
    int*            boff = (int*)(ws + off);            off += (MAXBUCK + 1) * 4;
    int*            bcur = (int*)(ws + off);            off += MAXBUCK * 4;
    float* outp = (float*)d_out;

    int histB = 256;
    int prepB = (128 * 160 + 32 * 128 + 20 + 255) / 256;
    int xcvB  = (N * 8 + 255) / 256;

    hipMemsetAsync(ghist, 0, MAXBUCK * 4, stream);
    fused_pre<<<histB + prepB + xcvB, 256, 0, stream>>>(
        dst, ghist, E, nbuck, Ws0, Wn0, Ws1, Wn1, B0t, B1t, bias, x, A0, N, histB, prepB);
    bucket_scan   <<<1, MAXBUCK, 0, stream>>>(ghist, boff, bcur, nbuck, E, rowp, N);
    bucket_scatter<<<256, 256, 0, stream>>>(src, dst, bcur, pairs, E);
    csr_finalize  <<<nbuck, 256, 0, stream>>>(pairs, boff, rowp, colb, N);

    agg0_kernel <<<(N + 3) / 4, 256, 0, stream>>>(rowp, colb, A0, N);
    gemm0_kernel<<<(N + 63) / 64, 256, 0, stream>>>(A0, B0t, h1, N);
    gemm1_kernel<<<(N + 127) / 128, 256, 0, stream>>>(h1, B1t, bias, S, Qp, N);
    final_kernel<<<(N + 255) / 256, 256, 0, stream>>>(S, Qp, rowp, colb, outp, N);
}

// Round 11
// 176.471 us; speedup vs baseline: 2.7156x; 1.0441x over previous
//
#include <hip/hip_runtime.h>
#include <hip/hip_bf16.h>
#include <math.h>

#define EPSN 1e-8f
#define MAXBUCK 512          // buckets of 128 nodes; requires N < 65536 (ushort col)

typedef __attribute__((ext_vector_type(8))) short short8;
typedef __attribute__((ext_vector_type(4))) float f32x4;

static __device__ __forceinline__ unsigned short f2bf(float f) {
    union { float f; unsigned int u; } v; v.f = f;
    unsigned int u = v.u;
    return (unsigned short)((u + 0x7fffu + ((u >> 16) & 1u)) >> 16);  // RNE
}
static __device__ __forceinline__ float bf2f(unsigned short h) {
    union { unsigned int u; float f; } v; v.u = ((unsigned int)h) << 16;
    return v.f;
}
static __device__ __forceinline__ unsigned int pk2(float a, float b) {
    return (((unsigned int)f2bf(b)) << 16) | (unsigned int)f2bf(a);
}

// ================= fused pre: bucket hist | weight prep | x->bf16 =================
__global__ void fused_pre(const int* __restrict__ dst, int* __restrict__ ghist, int E, int nbuck,
                          const float* __restrict__ Ws0, const float* __restrict__ Wn0,
                          const float* __restrict__ Ws1, const float* __restrict__ Wn1,
                          unsigned short* __restrict__ B0t, unsigned short* __restrict__ B1t,
                          float* __restrict__ bias,
                          const float* __restrict__ x, unsigned short* __restrict__ A0, int N,
                          int histB, int prepB) {
    int b = blockIdx.x;
    if (b < histB) {
        __shared__ int h[MAXBUCK];
        for (int i = threadIdx.x; i < MAXBUCK; i += 256) h[i] = 0;
        __syncthreads();
        int CH = (E + histB - 1) / histB;
        int lo = b * CH, hi = min(E, lo + CH);
        for (int e = lo + (int)threadIdx.x; e < hi; e += 256) atomicAdd(&h[dst[e] >> 7], 1);
        __syncthreads();
        for (int i = threadIdx.x; i < nbuck; i += 256) if (h[i]) atomicAdd(&ghist[i], h[i]);
        return;
    }
    if (b < histB + prepB) {
        int t = (b - histB) * 256 + threadIdx.x;
        if (t < 128 * 160) {
            int n = t / 160, k = t % 160;
            float v = 0.f;
            if (k < 64) v = Ws0[k * 128 + n];
            else if (k < 128) v = Wn0[(k - 64) * 128 + n];
            else if (k == 128) v = Ws0[64 * 128 + n];
            else if (k == 129) v = Wn0[64 * 128 + n];
            B0t[n * 160 + k] = f2bf(v);
        }
        int u = t - 128 * 160;
        if (u >= 0 && u < 32 * 128) {
            int c = u / 128, k = u % 128;
            float v = 0.f;
            if (c < 10) v = Ws1[k * 10 + c];
            else if (c < 20) v = Wn1[k * 10 + (c - 10)];
            B1t[c * 128 + k] = f2bf(v);
        }
        int w = t - 128 * 160 - 32 * 128;
        if (w >= 0 && w < 20) bias[w] = (w < 10) ? Ws1[128 * 10 + w] : Wn1[128 * 10 + (w - 10)];
        return;
    }
    int u = (b - histB - prepB) * 256 + threadIdx.x;   // u = n*8 + s
    if (u >= N * 8) return;
    int n = u >> 3, s = u & 7;
    const float4* xp = (const float4*)(x + (size_t)n * 64 + s * 8);
    float4 v0 = xp[0], v1 = xp[1];
    short8 r;
    r[0] = (short)f2bf(v0.x); r[1] = (short)f2bf(v0.y);
    r[2] = (short)f2bf(v0.z); r[3] = (short)f2bf(v0.w);
    r[4] = (short)f2bf(v1.x); r[5] = (short)f2bf(v1.y);
    r[6] = (short)f2bf(v1.z); r[7] = (short)f2bf(v1.w);
    *(short8*)(&A0[(size_t)n * 160 + s * 8]) = r;
}

// ================= bucket scan (1 block) =================
__global__ void bucket_scan(const int* __restrict__ ghist, int* __restrict__ boff,
                            int* __restrict__ bcur, int nbuck, int E,
                            int* __restrict__ row_ptr, int N) {
    __shared__ int bufa[MAXBUCK], bufb[MAXBUCK];
    int t = threadIdx.x;  // MAXBUCK threads
    int v = (t < nbuck) ? ghist[t] : 0;
    bufa[t] = v;
    __syncthreads();
    int* cur = bufa; int* nxt = bufb;
    for (int off = 1; off < MAXBUCK; off <<= 1) {
        int xv = cur[t];
        if (t >= off) xv += cur[t - off];
        nxt[t] = xv;
        __syncthreads();
        int* tmp = cur; cur = nxt; nxt = tmp;
    }
    int incl = cur[t];
    int excl = incl - v;
    if (t < nbuck) { boff[t] = excl; bcur[t] = excl; }
    if (t == nbuck - 1) boff[nbuck] = incl;   // == E
    if (t == 0) row_ptr[N] = E;
}

// ================= binned scatter of packed (local_dst<<16 | src) =================
__global__ void bucket_scatter(const int* __restrict__ src, const int* __restrict__ dst,
                               int* __restrict__ bcur, unsigned int* __restrict__ pairs,
                               int E) {
    __shared__ int h[MAXBUCK];
    __shared__ int bs[MAXBUCK];
    for (int i = threadIdx.x; i < MAXBUCK; i += 256) h[i] = 0;
    __syncthreads();
    int CH = (E + gridDim.x - 1) / gridDim.x;
    int lo = blockIdx.x * CH, hi = min(E, lo + CH);
    for (int e = lo + (int)threadIdx.x; e < hi; e += 256) atomicAdd(&h[dst[e] >> 7], 1);
    __syncthreads();
    for (int i = threadIdx.x; i < MAXBUCK; i += 256) {
        int c = h[i];
        bs[i] = c ? atomicAdd(&bcur[i], c) : 0;
        h[i] = 0;
    }
    __syncthreads();
    for (int e = lo + (int)threadIdx.x; e < hi; e += 256) {
        int d = dst[e];
        int b = d >> 7;
        int idx = atomicAdd(&h[b], 1);
        pairs[bs[b] + idx] = (((unsigned int)(d & 127)) << 16) | (unsigned int)src[e];
    }
}

// ================= per-bucket finalize -> row_ptr + ushort col =================
__global__ void csr_finalize(const unsigned int* __restrict__ pairs, const int* __restrict__ boff,
                             int* __restrict__ row_ptr, unsigned short* __restrict__ col,
                             int N) {
    __shared__ int lh[128], ls[128], lc[128];
    int b = blockIdx.x, t = threadIdx.x;  // 256 threads
    int lo = boff[b], hi = boff[b + 1];
    for (int i = t; i < 128; i += 256) lh[i] = 0;
    __syncthreads();
    for (int e = lo + t; e < hi; e += 256) atomicAdd(&lh[pairs[e] >> 16], 1);
    __syncthreads();
    if (t < 128) {
        int v = lh[t];
        int incl = v;
#pragma unroll
        for (int off = 1; off < 64; off <<= 1) {
            int y = __shfl_up(incl, off);
            if ((t & 63) >= off) incl += y;
        }
        ls[t] = incl;
    }
    __syncthreads();
    if (t < 128) {
        int v = lh[t];
        int excl = ls[t] - v + ((t >= 64) ? ls[63] : 0);
        int node = b * 128 + t;
        if (node < N) row_ptr[node] = lo + excl;
        lc[t] = excl;
    }
    __syncthreads();
    for (int e = lo + t; e < hi; e += 256) {
        unsigned int p = pairs[e];
        int ld = p >> 16;
        int idx = atomicAdd(&lc[ld], 1);
        col[lo + idx] = (unsigned short)(p & 0xFFFFu);
    }
}

// ================= agg0: wave-per-node gather-mean, 16-deep MLP =================
// lane = feature; chunked col load + shfl broadcast; 16 independent gathers in flight
__global__ void agg0_kernel(const int* __restrict__ row_ptr, const unsigned short* __restrict__ col,
                            unsigned short* __restrict__ A0, int N) {
    int n = (int)((blockIdx.x * blockDim.x + threadIdx.x) >> 6);
    if (n >= N) return;
    int lane = threadIdx.x & 63;
    int rs = row_ptr[n], re = row_ptr[n + 1];
    float acc = 0.f;
    for (int base = rs; base < re; base += 64) {
        int cnt = min(64, re - base);
        int e = 0;
        if (base + lane < re) e = (int)col[base + lane];
        int j = 0;
        for (; j + 16 <= cnt; j += 16) {
            float v[16];
#pragma unroll
            for (int i = 0; i < 16; ++i) {
                int s = __shfl(e, j + i);
                v[i] = bf2f(A0[(size_t)s * 160 + lane]);
            }
#pragma unroll
            for (int i = 0; i < 16; ++i) acc += v[i];
        }
        for (; j + 4 <= cnt; j += 4) {
            float v[4];
#pragma unroll
            for (int i = 0; i < 4; ++i) {
                int s = __shfl(e, j + i);
                v[i] = bf2f(A0[(size_t)s * 160 + lane]);
            }
#pragma unroll
            for (int i = 0; i < 4; ++i) acc += v[i];
        }
        for (; j < cnt; ++j) {
            int s = __shfl(e, j);
            acc += bf2f(A0[(size_t)s * 160 + lane]);
        }
    }
    float deg = (float)(re - rs);
    float scale = 1.0f / fmaxf(deg, 1.0f);
    unsigned short* row = A0 + (size_t)n * 160;
    row[64 + lane] = f2bf(acc * scale);                 // neigh cols 64..127
    if (lane == 0) *(unsigned int*)(&row[128]) = pk2(1.0f, deg * scale);  // (1.0, degscale)
    if (lane >= 1 && lane < 16) *(unsigned int*)(&row[128 + lane * 2]) = 0u;  // pad 130..159
}

// ================= GEMM0: h1 = relu(normalize(A0 @ B0)) =================
__global__ void __launch_bounds__(256)
gemm0_kernel(const unsigned short* __restrict__ A0, const unsigned short* __restrict__ B0t,
             unsigned short* __restrict__ h1, int N) {
    __shared__ unsigned short As[64 * 168];
    __shared__ unsigned short Bs[128 * 168];
    int t = threadIdx.x, blk = blockIdx.x;
    for (int i = t; i < 128 * 20; i += 256) {
        int r = i / 20, c = i % 20;
        *(uint4*)(&Bs[r * 168 + c * 8]) = *(const uint4*)(&B0t[r * 160 + c * 8]);
    }
    for (int i = t; i < 64 * 20; i += 256) {
        int r = i / 20, c = i % 20;
        int gr = blk * 64 + r;
        uint4 v = {0, 0, 0, 0};
        if (gr < N) v = *(const uint4*)(&A0[(size_t)gr * 160 + c * 8]);
        *(uint4*)(&As[r * 168 + c * 8]) = v;
    }
    __syncthreads();

    int wave = t >> 6, lane = t & 63;
    int lo = lane & 15, hi = lane >> 4;
    f32x4 acc[8];
#pragma unroll
    for (int f = 0; f < 8; ++f) acc[f] = (f32x4){0.f, 0.f, 0.f, 0.f};

#pragma unroll
    for (int ks = 0; ks < 5; ++ks) {
        short8 a = *(const short8*)(&As[(wave * 16 + lo) * 168 + ks * 32 + hi * 8]);
#pragma unroll
        for (int f = 0; f < 8; ++f) {
            short8 b = *(const short8*)(&Bs[(f * 16 + lo) * 168 + ks * 32 + hi * 8]);
            acc[f] = __builtin_amdgcn_mfma_f32_16x16x32_bf16(a, b, acc[f], 0, 0, 0);
        }
    }
#pragma unroll
    for (int j = 0; j < 4; ++j) {
        float s = 0.f;
#pragma unroll
        for (int f = 0; f < 8; ++f) s += acc[f][j] * acc[f][j];
#pragma unroll
        for (int m = 1; m < 16; m <<= 1) s += __shfl_xor(s, m);
        float inv = 1.0f / (sqrtf(s) + EPSN);
        int gr = blk * 64 + wave * 16 + hi * 4 + j;
        if (gr < N) {
#pragma unroll
            for (int f = 0; f < 8; ++f)
                h1[(size_t)gr * 128 + f * 16 + lo] = f2bf(fmaxf(acc[f][j] * inv, 0.f));
        }
    }
}

// ================= GEMM1: S[N][10] = h1@Ws1+b ; Qp[N][16] = [h1@Wn1+b | 0 pad] =================
__global__ void __launch_bounds__(256)
gemm1_kernel(const unsigned short* __restrict__ h1, const unsigned short* __restrict__ B1t,
             const float* __restrict__ bias, float* __restrict__ S, float* __restrict__ Qp, int N) {
    __shared__ unsigned short As[128 * 136];
    __shared__ unsigned short Bs[32 * 136];
    int t = threadIdx.x, blk = blockIdx.x;
    for (int i = t; i < 32 * 16; i += 256) {
        int r = i / 16, c = i % 16;
        *(uint4*)(&Bs[r * 136 + c * 8]) = *(const uint4*)(&B1t[r * 128 + c * 8]);
    }
    for (int i = t; i < 128 * 16; i += 256) {
        int r = i / 16, c = i % 16;
        int gr = blk * 128 + r;
        uint4 v = {0, 0, 0, 0};
        if (gr < N) v = *(const uint4*)(&h1[(size_t)gr * 128 + c * 8]);
        *(uint4*)(&As[r * 136 + c * 8]) = v;
    }
    __syncthreads();

    int wave = t >> 6, lane = t & 63, lo = lane & 15, hi = lane >> 4;
    f32x4 acc[2][2];
#pragma unroll
    for (int m = 0; m < 2; ++m) { acc[m][0] = (f32x4){0,0,0,0}; acc[m][1] = (f32x4){0,0,0,0}; }

#pragma unroll
    for (int ks = 0; ks < 4; ++ks) {
        short8 b0 = *(const short8*)(&Bs[lo * 136 + ks * 32 + hi * 8]);
        short8 b1 = *(const short8*)(&Bs[(16 + lo) * 136 + ks * 32 + hi * 8]);
#pragma unroll
        for (int m = 0; m < 2; ++m) {
            short8 a = *(const short8*)(&As[(wave * 32 + m * 16 + lo) * 136 + ks * 32 + hi * 8]);
            acc[m][0] = __builtin_amdgcn_mfma_f32_16x16x32_bf16(a, b0, acc[m][0], 0, 0, 0);
            acc[m][1] = __builtin_amdgcn_mfma_f32_16x16x32_bf16(a, b1, acc[m][1], 0, 0, 0);
        }
    }
#pragma unroll
    for (int m = 0; m < 2; ++m)
#pragma unroll
        for (int j = 0; j < 4; ++j) {
            int gr = blk * 128 + wave * 32 + m * 16 + hi * 4 + j;
            if (gr < N) {
                float v0 = acc[m][0][j] + bias[lo];
                if (lo < 10) S[(size_t)gr * 10 + lo] = v0;
                else         Qp[(size_t)gr * 16 + (lo - 10)] = v0;                          // cols 0..5
                if (lo < 4)       Qp[(size_t)gr * 16 + 6 + lo] = acc[m][1][j] + bias[16 + lo]; // 6..9
                else if (lo < 10) Qp[(size_t)gr * 16 + 6 + lo] = 0.f;                       // pad 10..15
            }
        }
}

// ================= final: thread-per-node; 4-edge unroll (12 loads in flight); log_softmax =================
__global__ void final_kernel(const float* __restrict__ S, const float* __restrict__ Qp,
                             const int* __restrict__ row_ptr, const unsigned short* __restrict__ col,
                             float* __restrict__ out, int N) {
    int n = blockIdx.x * blockDim.x + threadIdx.x;
    if (n >= N) return;
    int rs = row_ptr[n], re = row_ptr[n + 1];
    float q0 = 0.f, q1 = 0.f, q2 = 0.f, q3 = 0.f, q4 = 0.f;
    float q5 = 0.f, q6 = 0.f, q7 = 0.f, q8 = 0.f, q9 = 0.f;
    int e = rs;
    for (; e + 3 < re; e += 4) {
        float4 a[4], b[4]; float2 t2[4];
#pragma unroll
        for (int i = 0; i < 4; ++i) {
            int c = (int)col[e + i];
            const float4* r = (const float4*)(&Qp[(size_t)c * 16]);
            a[i] = r[0]; b[i] = r[1];
            t2[i] = *(const float2*)(&Qp[(size_t)c * 16 + 8]);
        }
#pragma unroll
        for (int i = 0; i < 4; ++i) {
            q0 += a[i].x; q1 += a[i].y; q2 += a[i].z; q3 += a[i].w;
            q4 += b[i].x; q5 += b[i].y; q6 += b[i].z; q7 += b[i].w;
            q8 += t2[i].x; q9 += t2[i].y;
        }
    }
    for (; e < re; ++e) {
        int c0 = (int)col[e];
        const float4* r0 = (const float4*)(&Qp[(size_t)c0 * 16]);
        float4 a0 = r0[0], b0 = r0[1];
        float2 t0 = *(const float2*)(&Qp[(size_t)c0 * 16 + 8]);
        q0 += a0.x; q1 += a0.y; q2 += a0.z; q3 += a0.w;
        q4 += b0.x; q5 += b0.y; q6 += b0.z; q7 += b0.w;
        q8 += t0.x; q9 += t0.y;
    }
    float deg = (float)(re - rs);
    float scale = 1.0f / fmaxf(deg, 1.0f);
    const float* Sr = &S[(size_t)n * 10];
    float p[10];
    p[0] = Sr[0] + q0 * scale; p[1] = Sr[1] + q1 * scale;
    p[2] = Sr[2] + q2 * scale; p[3] = Sr[3] + q3 * scale;
    p[4] = Sr[4] + q4 * scale; p[5] = Sr[5] + q5 * scale;
    p[6] = Sr[6] + q6 * scale; p[7] = Sr[7] + q7 * scale;
    p[8] = Sr[8] + q8 * scale; p[9] = Sr[9] + q9 * scale;
    float ss = 0.f;
#pragma unroll
    for (int j = 0; j < 10; ++j) ss = fmaf(p[j], p[j], ss);
    float inv = 1.0f / (sqrtf(ss) + EPSN);
    float m = -INFINITY;
#pragma unroll
    for (int j = 0; j < 10; ++j) { p[j] *= inv; m = fmaxf(m, p[j]); }
    float se = 0.f;
#pragma unroll
    for (int j = 0; j < 10; ++j) se += expf(p[j] - m);
    float ls = logf(se) + m;
#pragma unroll
    for (int j = 0; j < 10; ++j) out[(size_t)n * 10 + j] = p[j] - ls;
}

extern "C" void kernel_launch(void* const* d_in, const int* in_sizes, int n_in,
                              void* d_out, int out_size, void* d_ws, size_t ws_size,
                              hipStream_t stream) {
    const float* x   = (const float*)d_in[0];
    const int*   ei  = (const int*)d_in[1];
    const float* Ws0 = (const float*)d_in[2];
    const float* Wn0 = (const float*)d_in[3];
    const float* Ws1 = (const float*)d_in[4];
    const float* Wn1 = (const float*)d_in[5];

    int N = in_sizes[0] / 64;
    int E = in_sizes[1] / 2;
    const int* src = ei;
    const int* dst = ei + E;
    int nbuck = (N + 127) / 128;

    char* ws = (char*)d_ws;
    size_t off = 0;
    unsigned short* A0   = (unsigned short*)(ws + off); off += (size_t)N * 160 * 2;
    unsigned short* h1   = (unsigned short*)(ws + off); off += (size_t)N * 128 * 2;
    float*          S    = (float*)(ws + off);          off += (size_t)N * 10 * 4;
    float*          Qp   = (float*)(ws + off);          off += (size_t)N * 16 * 4;
    unsigned short* B0t  = (unsigned short*)(ws + off); off += 128 * 160 * 2;
    unsigned short* B1t  = (unsigned short*)(ws + off); off += 32 * 128 * 2;
    float*          bias = (float*)(ws + off);          off += 128;
    int*            rowp = (int*)(ws + off);            off += ((size_t)N + 4) * 4;
    unsigned short* colb = (unsigned short*)(ws + off); off += ((size_t)E + 8) * 2;
    unsigned int*   pairs= (unsigned int*)(ws + off);   off += (size_t)E * 4;
    int*            ghist= (int*)(ws + off);            off += MAXBUCK * 4;
    int*            boff = (int*)(ws + off);            off += (MAXBUCK + 1) * 4;
    int*            bcur = (int*)(ws + off);            off += MAXBUCK * 4;
    float* outp = (float*)d_out;

    int histB = 256;
    int prepB = (128 * 160 + 32 * 128 + 20 + 255) / 256;
    int xcvB  = (N * 8 + 255) / 256;

    hipMemsetAsync(ghist, 0, MAXBUCK * 4, stream);
    fused_pre<<<histB + prepB + xcvB, 256, 0, stream>>>(
        dst, ghist, E, nbuck, Ws0, Wn0, Ws1, Wn1, B0t, B1t, bias, x, A0, N, histB, prepB);
    bucket_scan   <<<1, MAXBUCK, 0, stream>>>(ghist, boff, bcur, nbuck, E, rowp, N);
    bucket_scatter<<<256, 256, 0, stream>>>(src, dst, bcur, pairs, E);
    csr_finalize  <<<nbuck, 256, 0, stream>>>(pairs, boff, rowp, colb, N);

    agg0_kernel <<<(N + 3) / 4, 256, 0, stream>>>(rowp, colb, A0, N);
    gemm0_kernel<<<(N + 63) / 64, 256, 0, stream>>>(A0, B0t, h1, N);
    gemm1_kernel<<<(N + 127) / 128, 256, 0, stream>>>(h1, B1t, bias, S, Qp, N);
    final_kernel<<<(N + 255) / 256, 256, 0, stream>>>(S, Qp, rowp, colb, outp, N);
}